// Round 11
// baseline (3009.897 us; speedup 1.0000x reference)
//
#include <hip/hip_runtime.h>
#include <hip/hip_bf16.h>

#define B_ 128
#define T_ 256
#define V_ 256
#define U_ 2048

typedef __bf16 bf16x8 __attribute__((ext_vector_type(8)));
typedef float f32x4 __attribute__((ext_vector_type(4)));

union B8u { uint4 u; bf16x8 v; };

static __device__ inline bf16x8 u2b(uint4 u) { B8u t; t.u = u; return t.v; }
static __device__ inline bf16x8 ldg8(const unsigned short* p) {
    B8u t; t.u = *reinterpret_cast<const uint4*>(p); return t.v;
}
static __device__ inline bf16x8 lds8(const char* smem, unsigned off) {
    B8u t; t.u = *reinterpret_cast<const uint4*>(smem + off); return t.v;
}
static __device__ inline unsigned short f2b(float f) {
    __hip_bfloat16 h = __float2bfloat16(f);
    unsigned short r; __builtin_memcpy(&r, &h, 2); return r;
}
// plain CACHED 16B load as volatile asm: compiler cannot sink it into the
// consumer loop (R3/R4 lesson: sunk loads = serialized latency chain)
static __device__ inline uint4 ldg16_c(const unsigned short* p) {
    uint4 r;
    asm volatile("global_load_dwordx4 %0, %1, off"
                 : "=&v"(r) : "v"(p) : "memory");
    return r;
}
// 8B write-through to L3 coherence point
static __device__ inline void stg8_sc(unsigned short* p, uint2 v) {
    asm volatile("global_store_dwordx2 %0, %1, off sc0 sc1"
                 :: "v"(p), "v"(v) : "memory");
}
// 4B flag store, write-through (fire-and-forget arrive)
static __device__ inline void stg4_sc_u32(unsigned* p, unsigned v) {
    asm volatile("global_store_dword %0, %1, off sc0 sc1"
                 :: "v"(p), "v"(v) : "memory");
}
// 16B coherent flag load with its own waitcnt (self-contained poll probe)
static __device__ inline uint4 ldg16_sc_wait(const unsigned* p) {
    uint4 r;
    asm volatile("global_load_dwordx4 %0, %1, off sc0 sc1\n\ts_waitcnt vmcnt(0)"
                 : "=&v"(r) : "v"(p) : "memory");
    return r;
}
// tanh via hw exp+rcp: ~5 VALU ops vs ~20 for tanhf; exact at saturation
// (e=inf -> 1; e=0 -> -1), error ~2ulp f32 << bf16 rounding
static __device__ inline float tanh_fast(float x) {
    float e = __expf(2.0f * x);
    return 1.0f - 2.0f * __builtin_amdgcn_rcpf(e + 1.0f);
}

// ---------------- prep kernels ----------------

// out[c][r] = bf16(in[r][c]);  in: [R][C] f32, out: [C][R] bf16
__global__ void transpose_bf16(const float* __restrict__ in,
                               unsigned short* __restrict__ outp, int R, int C) {
    __shared__ float tile[32][33];
    int tc = blockIdx.x * 32, tr = blockIdx.y * 32;
    int lx = threadIdx.x & 31, ly = threadIdx.x >> 5;  // 256 thr: ly 0..7
#pragma unroll
    for (int i = 0; i < 32; i += 8)
        tile[ly + i][lx] = in[(size_t)(tr + ly + i) * C + tc + lx];
    __syncthreads();
#pragma unroll
    for (int i = 0; i < 32; i += 8)
        outp[(size_t)(tc + ly + i) * R + tr + lx] = f2b(tile[lx][ly + i]);
}

__global__ void conv_h0(const float* __restrict__ h0, unsigned short* __restrict__ hb) {
    int i = blockIdx.x * blockDim.x + threadIdx.x;  // grid covers exactly B_*U_
    hb[i] = f2b(h0[i]);
}

// xT[t][b] = x[b][t]
__global__ void transpose_x(const int* __restrict__ x, int* __restrict__ xT) {
    int i = blockIdx.x * 256 + threadIdx.x;  // grid: 128 blocks
    int b = i >> 8, t = i & 255;
    xT[t * B_ + b] = x[i];
}

// =====================================================================
// Recurrence kernel -- per-wave FLAG barrier (R10 core + cheap sync).
// grid: 256 blocks (4 groups x 64), 256 threads (4 waves), 1 block/CU.
// Block (g,p): batches b0=g*32..+32, u-cols c0=p*32..+32.
// Wave w: K-quarter [w*512, +512) -> LDS f32 reduce across waves.
//
// Sync redesign vs R10 (which RMW'd 8 sub-counters + 3 syncthreads/step):
//  - arrive: each WAVE, after draining ITS OWN h-stores (vmcnt is per-wave),
//    fire-and-forget stores flags[g][p][w] = t+1. No RMW, no sync#2, no
//    final syncthreads.
//  - poll: every wave independently; lane l dwordx4-loads block l's 4
//    wave-flags (256 flags = 1KB contiguous, one parallel L3 trip);
//    __all(min4 > t) -> proceed. Staggered self-release.
//  - LDS hazard ordering (S's reduce-read(t) vs F's partial-write(t+1))
//    is carried by the flag: F's write > F's poll-pass > S's flag-set >
//    S's drain > S's reduce-read. Only sync#1 (partials->reduce) remains.
// h_t stores: sc0sc1 write-through to fresh hs[t+1] (archive -> plain
// cached reads never stale: any hit is current or bit-identical replay).
// =====================================================================
__global__ __launch_bounds__(256, 1) void rnn_arc7(
        const int* __restrict__ xT, const float* __restrict__ Wx,
        const float* __restrict__ bias, const unsigned short* __restrict__ WhT,
        unsigned short* __restrict__ hs, unsigned* __restrict__ flags) {
    extern __shared__ char smem[];
    float* red = (float*)(smem + 32 * 2048 * 2);  // [4][32*36] f32

    const int bid = blockIdx.x;
    const int g = bid >> 6, p = bid & 63;
    const int b0 = g * 32, c0 = p * 32;
    const int tid = threadIdx.x;
    const int w = tid >> 6, lane = tid & 63;
    const int lr = lane & 15, lh = lane >> 4;

    // Fill Wh LDS slice: lds[(c*4096 + k8*16) ^ ((c&7)<<4)] = WhT[c0+c][k8*8..+8]
    for (int i = tid; i < 32 * 256; i += 256) {
        int c = i >> 8, k8 = i & 255;
        uint4 v = *reinterpret_cast<const uint4*>(WhT + (size_t)(c0 + c) * U_ + k8 * 8);
        unsigned off = (unsigned)(c * 4096 + k8 * 16) ^ ((unsigned)(c & 7) << 4);
        *reinterpret_cast<uint4*>(smem + off) = v;
    }
    __syncthreads();

    // MFMA-loop constants (wave-local K-quarter)
    const int kbase = w * 512;
    const unsigned lin0 = (unsigned)(lr * 4096) + (unsigned)((kbase + lh * 8) * 2);
    const unsigned lin1 = lin0 + 16 * 4096;
    const unsigned swz = (unsigned)(lr & 7) << 4;

    // epilogue constants: thread -> (row = tid>>3, 4 contiguous cols)
    const int erow = tid >> 3;              // 0..31 local batch row
    const int ec4 = (tid & 7) * 4;          // 0..28 local col (x4)
    const int ucol = c0 + ec4;              // global u column of 4-pack
    const f32x4 bias4 = *reinterpret_cast<const f32x4*>(bias + ucol);

    // sync addresses
    unsigned* myflag = flags + (unsigned)(g * 256 + p * 4 + w);
    const unsigned* pollp = flags + (unsigned)(g * 256 + lane * 4);

    // x-projection for step 0
    f32x4 xp;
    {
        int tok = xT[0 * B_ + b0 + erow];
        xp = *reinterpret_cast<const f32x4*>(Wx + (size_t)tok * U_ + ucol) + bias4;
    }

    for (int t = 0; t < T_; ++t) {
        const unsigned short* hp = hs + (size_t)t * (B_ * U_);
        unsigned short* hc = hs + (size_t)(t + 1) * (B_ * U_);

        // ---- stage all 32 A-fragments upfront: forced parallel issue ----
        const unsigned short* pa0 = hp + (size_t)(b0 + lr) * U_ + kbase + lh * 8;
        const unsigned short* pa1 = pa0 + 16 * U_;
        uint4 areg0[16], areg1[16];
#pragma unroll
        for (int ks = 0; ks < 16; ++ks) {
            areg0[ks] = ldg16_c(pa0 + ks * 32);
            areg1[ks] = ldg16_c(pa1 + ks * 32);
        }
        asm volatile("s_waitcnt vmcnt(0)" ::: "memory");
        __builtin_amdgcn_sched_barrier(0);

        // ---- load-free MFMA loop over the K-quarter ----
        f32x4 acc00 = {0.f, 0.f, 0.f, 0.f}, acc01 = {0.f, 0.f, 0.f, 0.f};
        f32x4 acc10 = {0.f, 0.f, 0.f, 0.f}, acc11 = {0.f, 0.f, 0.f, 0.f};
#pragma unroll
        for (int ks = 0; ks < 16; ++ks) {
            bf16x8 a0 = u2b(areg0[ks]);
            bf16x8 a1 = u2b(areg1[ks]);
            bf16x8 bb0 = lds8(smem, (lin0 + (unsigned)ks * 64u) ^ swz);
            bf16x8 bb1 = lds8(smem, (lin1 + (unsigned)ks * 64u) ^ swz);
            acc00 = __builtin_amdgcn_mfma_f32_16x16x32_bf16(a0, bb0, acc00, 0, 0, 0);
            acc01 = __builtin_amdgcn_mfma_f32_16x16x32_bf16(a0, bb1, acc01, 0, 0, 0);
            acc10 = __builtin_amdgcn_mfma_f32_16x16x32_bf16(a1, bb0, acc10, 0, 0, 0);
            acc11 = __builtin_amdgcn_mfma_f32_16x16x32_bf16(a1, bb1, acc11, 0, 0, 0);
        }

        // ---- split-K partials -> LDS (2-way bank pattern, free) ----
        float* redw = red + w * 1152;
#pragma unroll
        for (int r = 0; r < 4; ++r) {
            redw[(lh * 4 + r) * 36 + lr] = acc00[r];
            redw[(lh * 4 + r) * 36 + 16 + lr] = acc01[r];
            redw[(16 + lh * 4 + r) * 36 + lr] = acc10[r];
            redw[(16 + lh * 4 + r) * 36 + 16 + lr] = acc11[r];
        }
        __syncthreads();  // sync#1: partials visible for the reduce

        // next step's x-projection: issue BEFORE the reduce so its latency
        // hides under the reduce/tanh instead of inside the store drain
        f32x4 xpn = xp;
        if (t + 1 < T_) {
            int tok = xT[(t + 1) * B_ + b0 + erow];
            xpn = *reinterpret_cast<const f32x4*>(Wx + (size_t)tok * U_ + ucol) + bias4;
        }

        // ---- reduce (float4) + tanh + one dwordx2 sc store per thread ----
        {
            const int o = erow * 36 + ec4;
            f32x4 z = *reinterpret_cast<f32x4*>(red + 0 * 1152 + o);
            z += *reinterpret_cast<f32x4*>(red + 1 * 1152 + o);
            z += *reinterpret_cast<f32x4*>(red + 2 * 1152 + o);
            z += *reinterpret_cast<f32x4*>(red + 3 * 1152 + o);
            z += xp;
            unsigned lo = (unsigned)f2b(tanh_fast(z[0])) |
                          ((unsigned)f2b(tanh_fast(z[1])) << 16);
            unsigned hi = (unsigned)f2b(tanh_fast(z[2])) |
                          ((unsigned)f2b(tanh_fast(z[3])) << 16);
            stg8_sc(hc + (size_t)(b0 + erow) * U_ + ucol, make_uint2(lo, hi));
        }
        xp = xpn;

        // ---- per-wave drain + fire-and-forget arrive (no RMW, no sync) ----
        asm volatile("s_waitcnt vmcnt(0)" ::: "memory");
        if (lane == 0) stg4_sc_u32(myflag, (unsigned)(t + 1));

        // ---- poll: all 256 wave-flags of the group >= t+1; every wave
        //      self-releases (staggered). Skipped on the final step. ----
        if (t + 1 < T_) {
            for (;;) {
                uint4 f = ldg16_sc_wait(pollp);
                unsigned m01 = f.x < f.y ? f.x : f.y;
                unsigned m23 = f.z < f.w ? f.z : f.w;
                unsigned m = m01 < m23 ? m01 : m23;
                if (__all(m > (unsigned)t)) break;
            }
        }
    }
}

// =====================================================================
// Decode GEMM v2: logits[b,t,v] = hs[t+1][b] . WdT[v] + bd[v]
// hsD = hs + B*U viewed as [T*B][U]; out row = (b*T + t).
// 1024 blocks x 4 waves; wave = 32 rows x 64 cols (acc 32 VGPR, 6 loads +
// 8 MFMA per k-step) -> 2 blocks/CU, TLP hides sunk-load latency.
// =====================================================================
__global__ __launch_bounds__(256, 2) void decode_gemm2(
        const unsigned short* __restrict__ hsD, const unsigned short* __restrict__ WdT,
        const float* __restrict__ bdv, float* __restrict__ out) {
    const int tid = threadIdx.x;
    const int w = tid >> 6, lane = tid & 63;
    const int lr = lane & 15, lh = lane >> 4;
    const int r0 = blockIdx.x * 32;   // 32 hsD rows per block
    const int v0 = w * 64;            // 64 vocab cols per wave

    const unsigned short* pa0 = hsD + (size_t)(r0 + lr) * U_ + lh * 8;
    const unsigned short* pa1 = pa0 + (size_t)16 * U_;
    const unsigned short* pb0 = WdT + (size_t)(v0 + lr) * U_ + lh * 8;

    f32x4 acc0[4], acc1[4];
#pragma unroll
    for (int n = 0; n < 4; ++n) {
        acc0[n] = (f32x4){0.f, 0.f, 0.f, 0.f};
        acc1[n] = (f32x4){0.f, 0.f, 0.f, 0.f};
    }

#pragma unroll 4
    for (int ks = 0; ks < 64; ++ks) {
        bf16x8 a0 = ldg8(pa0 + ks * 32);
        bf16x8 a1 = ldg8(pa1 + ks * 32);
#pragma unroll
        for (int n = 0; n < 4; ++n) {
            bf16x8 bb = ldg8(pb0 + (size_t)n * 16 * U_ + ks * 32);
            acc0[n] = __builtin_amdgcn_mfma_f32_16x16x32_bf16(a0, bb, acc0[n], 0, 0, 0);
            acc1[n] = __builtin_amdgcn_mfma_f32_16x16x32_bf16(a1, bb, acc1[n], 0, 0, 0);
        }
    }

#pragma unroll
    for (int n = 0; n < 4; ++n) {
        float bd_ = bdv[v0 + n * 16 + lr];
#pragma unroll
        for (int r = 0; r < 4; ++r) {
            int m0 = r0 + lh * 4 + r;        // hsD row = t*B + b
            int m1 = m0 + 16;
            out[((size_t)(m0 & 127) * T_ + (m0 >> 7)) * V_ + v0 + n * 16 + lr] =
                acc0[n][r] + bd_;
            out[((size_t)(m1 & 127) * T_ + (m1 >> 7)) * V_ + v0 + n * 16 + lr] =
                acc1[n][r] + bd_;
        }
    }
}

// ---------------- launch ----------------
extern "C" void kernel_launch(void* const* d_in, const int* in_sizes, int n_in,
                              void* d_out, int out_size, void* d_ws, size_t ws_size,
                              hipStream_t stream) {
    const int* x = (const int*)d_in[0];
    const float* Wx = (const float*)d_in[1];
    const float* Wh = (const float*)d_in[2];
    const float* b = (const float*)d_in[3];
    const float* Wd = (const float*)d_in[4];
    const float* bd = (const float*)d_in[5];
    const float* h0 = (const float*)d_in[6];
    float* out = (float*)d_out;

    char* ws = (char*)d_ws;

    const size_t OFF_WhT = 0;                 // 8,388,608
    const size_t OFF_WdT = 8388608;           // 1,048,576
    const size_t OFF_xT = 9437184;            // 131,072
    const size_t OFF_FLG = 9568256;           // 4,096 (4 grp x 64 blk x 4 wave)
    const size_t OFF_HS = 9572352;            // 257 * 524,288

    unsigned short* WhT = (unsigned short*)(ws + OFF_WhT);
    unsigned short* WdT = (unsigned short*)(ws + OFF_WdT);
    int* xT = (int*)(ws + OFF_xT);
    unsigned* flags = (unsigned*)(ws + OFF_FLG);
    unsigned short* hs = (unsigned short*)(ws + OFF_HS);

    hipMemsetAsync(flags, 0, 4096, stream);
    transpose_bf16<<<dim3(64, 64), 256, 0, stream>>>(Wh, WhT, 2048, 2048);
    transpose_bf16<<<dim3(8, 64), 256, 0, stream>>>(Wd, WdT, 2048, 256);
    conv_h0<<<1024, 256, 0, stream>>>(h0, hs);  // h_{-1} -> hs[0]
    transpose_x<<<128, 256, 0, stream>>>(x, xT);

    const int smem_bytes = 32 * 2048 * 2 + 4 * 1152 * 4;  // 149,504 B
    hipFuncSetAttribute((const void*)rnn_arc7, hipFuncAttributeMaxDynamicSharedMemorySize,
                        smem_bytes);
    void* args[] = {(void*)&xT, (void*)&Wx, (void*)&b, (void*)&WhT, (void*)&hs,
                    (void*)&flags};
    hipLaunchCooperativeKernel((const void*)rnn_arc7, dim3(256), dim3(256), args,
                               (unsigned)smem_bytes, stream);

    const unsigned short* hsD = hs + (size_t)B_ * U_;
    decode_gemm2<<<1024, 256, 0, stream>>>(hsD, WdT, bd, out);
}

// Round 12
// 1873.375 us; speedup vs baseline: 1.6067x; 1.6067x over previous
//
#include <hip/hip_runtime.h>
#include <hip/hip_bf16.h>

#define B_ 128
#define T_ 256
#define V_ 256
#define U_ 2048

typedef __bf16 bf16x8 __attribute__((ext_vector_type(8)));
typedef float f32x4 __attribute__((ext_vector_type(4)));

union B8u { uint4 u; bf16x8 v; };

static __device__ inline bf16x8 u2b(uint4 u) { B8u t; t.u = u; return t.v; }
static __device__ inline bf16x8 ldg8(const unsigned short* p) {
    B8u t; t.u = *reinterpret_cast<const uint4*>(p); return t.v;
}
static __device__ inline bf16x8 lds8(const char* smem, unsigned off) {
    B8u t; t.u = *reinterpret_cast<const uint4*>(smem + off); return t.v;
}
static __device__ inline unsigned short f2b(float f) {
    __hip_bfloat16 h = __float2bfloat16(f);
    unsigned short r; __builtin_memcpy(&r, &h, 2); return r;
}
// plain CACHED 16B load as volatile asm: compiler cannot sink it into the
// consumer loop (R3/R4 lesson: sunk loads = serialized latency chain)
static __device__ inline uint4 ldg16_c(const unsigned short* p) {
    uint4 r;
    asm volatile("global_load_dwordx4 %0, %1, off"
                 : "=&v"(r) : "v"(p) : "memory");
    return r;
}
// 8B write-through to L3 coherence point
static __device__ inline void stg8_sc(unsigned short* p, uint2 v) {
    asm volatile("global_store_dwordx2 %0, %1, off sc0 sc1"
                 :: "v"(p), "v"(v) : "memory");
}
// 4B flag store, write-through (fire-and-forget arrive)
static __device__ inline void stg4_sc_u32(unsigned* p, unsigned v) {
    asm volatile("global_store_dword %0, %1, off sc0 sc1"
                 :: "v"(p), "v"(v) : "memory");
}
// 16B coherent flag load with its own waitcnt (self-contained poll probe)
static __device__ inline uint4 ldg16_sc_wait(const unsigned* p) {
    uint4 r;
    asm volatile("global_load_dwordx4 %0, %1, off sc0 sc1\n\ts_waitcnt vmcnt(0)"
                 : "=&v"(r) : "v"(p) : "memory");
    return r;
}

// ---------------- prep kernels ----------------

// out[c][r] = bf16(in[r][c]);  in: [R][C] f32, out: [C][R] bf16
__global__ void transpose_bf16(const float* __restrict__ in,
                               unsigned short* __restrict__ outp, int R, int C) {
    __shared__ float tile[32][33];
    int tc = blockIdx.x * 32, tr = blockIdx.y * 32;
    int lx = threadIdx.x & 31, ly = threadIdx.x >> 5;  // 256 thr: ly 0..7
#pragma unroll
    for (int i = 0; i < 32; i += 8)
        tile[ly + i][lx] = in[(size_t)(tr + ly + i) * C + tc + lx];
    __syncthreads();
#pragma unroll
    for (int i = 0; i < 32; i += 8)
        outp[(size_t)(tc + ly + i) * R + tr + lx] = f2b(tile[lx][ly + i]);
}

__global__ void conv_h0(const float* __restrict__ h0, unsigned short* __restrict__ hb) {
    int i = blockIdx.x * blockDim.x + threadIdx.x;  // grid covers exactly B_*U_
    hb[i] = f2b(h0[i]);
}

// xT[t][b] = x[b][t]
__global__ void transpose_x(const int* __restrict__ x, int* __restrict__ xT) {
    int i = blockIdx.x * 256 + threadIdx.x;  // grid: 128 blocks
    int b = i >> 8, t = i & 255;
    xT[t * B_ + b] = x[i];
}

// =====================================================================
// Recurrence kernel -- R10 core, with ONE isolated sync change:
//   arrive = per-wave vmcnt drain + fire-and-forget flag store
//   (replaces R10's {vmcnt drain + syncthreads join + tid0 atomic RMW}).
// Release stays R10-style: wave 0 polls WITH s_sleep(1) backoff (R11's
// regression was the backoff-less all-wave spin flooding L3), then
// __syncthreads() (whose implicit full waitcnt+barrier also provides the
// intra-block LDS ordering for red reuse).
//
// grid: 256 blocks (4 groups x 64), 256 threads (4 waves), 1 block/CU.
// Block (g,p): batches b0=g*32..+32, u-cols c0=p*32..+32.
// Wave w: K-quarter [w*512, +512) -> LDS f32 reduce across waves.
// A loads: plain cached, forced batch-issue via asm, single vmcnt(0).
// h stores: sc0sc1 write-through to fresh hs[t+1] (archive -> plain cached
// reads never stale: any hit is current or bit-identical prior replay).
// =====================================================================
__global__ __launch_bounds__(256, 1) void rnn_arc8(
        const int* __restrict__ xT, const float* __restrict__ Wx,
        const float* __restrict__ bias, const unsigned short* __restrict__ WhT,
        unsigned short* __restrict__ hs, unsigned* __restrict__ flags) {
    extern __shared__ char smem[];
    float* red = (float*)(smem + 32 * 2048 * 2);  // [4][32*36] f32

    const int bid = blockIdx.x;
    const int g = bid >> 6, p = bid & 63;
    const int b0 = g * 32, c0 = p * 32;
    const int tid = threadIdx.x;
    const int w = tid >> 6, lane = tid & 63;
    const int lr = lane & 15, lh = lane >> 4;

    // Fill Wh LDS slice: lds[(c*4096 + k8*16) ^ ((c&7)<<4)] = WhT[c0+c][k8*8..+8]
    for (int i = tid; i < 32 * 256; i += 256) {
        int c = i >> 8, k8 = i & 255;
        uint4 v = *reinterpret_cast<const uint4*>(WhT + (size_t)(c0 + c) * U_ + k8 * 8);
        unsigned off = (unsigned)(c * 4096 + k8 * 16) ^ ((unsigned)(c & 7) << 4);
        *reinterpret_cast<uint4*>(smem + off) = v;
    }
    __syncthreads();

    // MFMA-loop constants (wave-local K-quarter)
    const int kbase = w * 512;
    const unsigned lin0 = (unsigned)(lr * 4096) + (unsigned)((kbase + lh * 8) * 2);
    const unsigned lin1 = lin0 + 16 * 4096;
    const unsigned swz = (unsigned)(lr & 7) << 4;

    // epilogue constants: thread -> (row = tid>>3, 4 contiguous cols)
    const int erow = tid >> 3;              // 0..31 local batch row
    const int ec4 = (tid & 7) * 4;          // 0..28 local col (x4)
    const int ucol = c0 + ec4;              // global u column of 4-pack
    const f32x4 bias4 = *reinterpret_cast<const f32x4*>(bias + ucol);

    // sync addresses: flags[g][p][w], poll covers the group's 256 wave-flags
    unsigned* myflag = flags + (unsigned)(g * 256 + p * 4 + w);
    const unsigned* pollp = flags + (unsigned)(g * 256 + lane * 4);

    // x-projection for step 0
    f32x4 xp;
    {
        int tok = xT[0 * B_ + b0 + erow];
        xp = *reinterpret_cast<const f32x4*>(Wx + (size_t)tok * U_ + ucol) + bias4;
    }

    for (int t = 0; t < T_; ++t) {
        const unsigned short* hp = hs + (size_t)t * (B_ * U_);
        unsigned short* hc = hs + (size_t)(t + 1) * (B_ * U_);

        // ---- stage all 32 A-fragments upfront: forced parallel issue ----
        const unsigned short* pa0 = hp + (size_t)(b0 + lr) * U_ + kbase + lh * 8;
        const unsigned short* pa1 = pa0 + 16 * U_;
        uint4 areg0[16], areg1[16];
#pragma unroll
        for (int ks = 0; ks < 16; ++ks) {
            areg0[ks] = ldg16_c(pa0 + ks * 32);
            areg1[ks] = ldg16_c(pa1 + ks * 32);
        }
        asm volatile("s_waitcnt vmcnt(0)" ::: "memory");
        __builtin_amdgcn_sched_barrier(0);

        // ---- load-free MFMA loop over the K-quarter ----
        f32x4 acc00 = {0.f, 0.f, 0.f, 0.f}, acc01 = {0.f, 0.f, 0.f, 0.f};
        f32x4 acc10 = {0.f, 0.f, 0.f, 0.f}, acc11 = {0.f, 0.f, 0.f, 0.f};
#pragma unroll
        for (int ks = 0; ks < 16; ++ks) {
            bf16x8 a0 = u2b(areg0[ks]);
            bf16x8 a1 = u2b(areg1[ks]);
            bf16x8 bb0 = lds8(smem, (lin0 + (unsigned)ks * 64u) ^ swz);
            bf16x8 bb1 = lds8(smem, (lin1 + (unsigned)ks * 64u) ^ swz);
            acc00 = __builtin_amdgcn_mfma_f32_16x16x32_bf16(a0, bb0, acc00, 0, 0, 0);
            acc01 = __builtin_amdgcn_mfma_f32_16x16x32_bf16(a0, bb1, acc01, 0, 0, 0);
            acc10 = __builtin_amdgcn_mfma_f32_16x16x32_bf16(a1, bb0, acc10, 0, 0, 0);
            acc11 = __builtin_amdgcn_mfma_f32_16x16x32_bf16(a1, bb1, acc11, 0, 0, 0);
        }

        // ---- split-K partials -> LDS (2-way bank pattern, free) ----
        float* redw = red + w * 1152;
#pragma unroll
        for (int r = 0; r < 4; ++r) {
            redw[(lh * 4 + r) * 36 + lr] = acc00[r];
            redw[(lh * 4 + r) * 36 + 16 + lr] = acc01[r];
            redw[(16 + lh * 4 + r) * 36 + lr] = acc10[r];
            redw[(16 + lh * 4 + r) * 36 + 16 + lr] = acc11[r];
        }
        __syncthreads();  // sync#1: partials visible for the reduce

        // ---- reduce (float4) + tanh + one dwordx2 sc store per thread ----
        {
            const int o = erow * 36 + ec4;
            f32x4 z = *reinterpret_cast<f32x4*>(red + 0 * 1152 + o);
            z += *reinterpret_cast<f32x4*>(red + 1 * 1152 + o);
            z += *reinterpret_cast<f32x4*>(red + 2 * 1152 + o);
            z += *reinterpret_cast<f32x4*>(red + 3 * 1152 + o);
            z += xp;
            unsigned lo = (unsigned)f2b(tanhf(z[0])) | ((unsigned)f2b(tanhf(z[1])) << 16);
            unsigned hi = (unsigned)f2b(tanhf(z[2])) | ((unsigned)f2b(tanhf(z[3])) << 16);
            stg8_sc(hc + (size_t)(b0 + erow) * U_ + ucol, make_uint2(lo, hi));
        }

        // ---- arrive: per-wave drain of MY h-stores, then one flag store.
        //      No block join, no atomic RMW (the R12 experiment). ----
        asm volatile("s_waitcnt vmcnt(0)" ::: "memory");
        if (lane == 0) stg4_sc_u32(myflag, (unsigned)(t + 1));

        // next step's x-projection: issued in the poll window; its latency
        // is covered by next step's vmcnt(0)
        if (t + 1 < T_) {
            int tok = xT[(t + 1) * B_ + b0 + erow];
            xp = *reinterpret_cast<const f32x4*>(Wx + (size_t)tok * U_ + ucol) + bias4;
        }

        // ---- release: wave 0 polls all 256 group wave-flags (64 lanes x
        //      dwordx4 = one probe) WITH s_sleep backoff; others sleep at
        //      the barrier. syncthreads' implicit full drain also orders
        //      red reads (this step) vs red writes (next step). ----
        if (t + 1 < T_) {
            if (w == 0) {
                for (;;) {
                    uint4 f = ldg16_sc_wait(pollp);
                    unsigned m01 = f.x < f.y ? f.x : f.y;
                    unsigned m23 = f.z < f.w ? f.z : f.w;
                    unsigned m = m01 < m23 ? m01 : m23;
                    if (__all(m > (unsigned)t)) break;
                    __builtin_amdgcn_s_sleep(1);
                }
            }
            __syncthreads();
        }
    }
}

// =====================================================================
// Decode GEMM v2 (proven in R10): logits[b,t,v] = hs[t+1][b].WdT[v] + bd[v]
// hsD = hs + B*U viewed as [T*B][U]; out row = (b*T + t).
// 1024 blocks x 4 waves; wave = 32 rows x 64 cols; 2 blocks/CU TLP.
// =====================================================================
__global__ __launch_bounds__(256, 2) void decode_gemm2(
        const unsigned short* __restrict__ hsD, const unsigned short* __restrict__ WdT,
        const float* __restrict__ bdv, float* __restrict__ out) {
    const int tid = threadIdx.x;
    const int w = tid >> 6, lane = tid & 63;
    const int lr = lane & 15, lh = lane >> 4;
    const int r0 = blockIdx.x * 32;   // 32 hsD rows per block
    const int v0 = w * 64;            // 64 vocab cols per wave

    const unsigned short* pa0 = hsD + (size_t)(r0 + lr) * U_ + lh * 8;
    const unsigned short* pa1 = pa0 + (size_t)16 * U_;
    const unsigned short* pb0 = WdT + (size_t)(v0 + lr) * U_ + lh * 8;

    f32x4 acc0[4], acc1[4];
#pragma unroll
    for (int n = 0; n < 4; ++n) {
        acc0[n] = (f32x4){0.f, 0.f, 0.f, 0.f};
        acc1[n] = (f32x4){0.f, 0.f, 0.f, 0.f};
    }

#pragma unroll 4
    for (int ks = 0; ks < 64; ++ks) {
        bf16x8 a0 = ldg8(pa0 + ks * 32);
        bf16x8 a1 = ldg8(pa1 + ks * 32);
#pragma unroll
        for (int n = 0; n < 4; ++n) {
            bf16x8 bb = ldg8(pb0 + (size_t)n * 16 * U_ + ks * 32);
            acc0[n] = __builtin_amdgcn_mfma_f32_16x16x32_bf16(a0, bb, acc0[n], 0, 0, 0);
            acc1[n] = __builtin_amdgcn_mfma_f32_16x16x32_bf16(a1, bb, acc1[n], 0, 0, 0);
        }
    }

#pragma unroll
    for (int n = 0; n < 4; ++n) {
        float bd_ = bdv[v0 + n * 16 + lr];
#pragma unroll
        for (int r = 0; r < 4; ++r) {
            int m0 = r0 + lh * 4 + r;        // hsD row = t*B + b
            int m1 = m0 + 16;
            out[((size_t)(m0 & 127) * T_ + (m0 >> 7)) * V_ + v0 + n * 16 + lr] =
                acc0[n][r] + bd_;
            out[((size_t)(m1 & 127) * T_ + (m1 >> 7)) * V_ + v0 + n * 16 + lr] =
                acc1[n][r] + bd_;
        }
    }
}

// ---------------- launch ----------------
extern "C" void kernel_launch(void* const* d_in, const int* in_sizes, int n_in,
                              void* d_out, int out_size, void* d_ws, size_t ws_size,
                              hipStream_t stream) {
    const int* x = (const int*)d_in[0];
    const float* Wx = (const float*)d_in[1];
    const float* Wh = (const float*)d_in[2];
    const float* b = (const float*)d_in[3];
    const float* Wd = (const float*)d_in[4];
    const float* bd = (const float*)d_in[5];
    const float* h0 = (const float*)d_in[6];
    float* out = (float*)d_out;

    char* ws = (char*)d_ws;

    const size_t OFF_WhT = 0;                 // 8,388,608
    const size_t OFF_WdT = 8388608;           // 1,048,576
    const size_t OFF_xT = 9437184;            // 131,072
    const size_t OFF_FLG = 9568256;           // 4,096 (4 grp x 64 blk x 4 wave)
    const size_t OFF_HS = 9572352;            // 257 * 524,288

    unsigned short* WhT = (unsigned short*)(ws + OFF_WhT);
    unsigned short* WdT = (unsigned short*)(ws + OFF_WdT);
    int* xT = (int*)(ws + OFF_xT);
    unsigned* flags = (unsigned*)(ws + OFF_FLG);
    unsigned short* hs = (unsigned short*)(ws + OFF_HS);

    hipMemsetAsync(flags, 0, 4096, stream);
    transpose_bf16<<<dim3(64, 64), 256, 0, stream>>>(Wh, WhT, 2048, 2048);
    transpose_bf16<<<dim3(8, 64), 256, 0, stream>>>(Wd, WdT, 2048, 256);
    conv_h0<<<1024, 256, 0, stream>>>(h0, hs);  // h_{-1} -> hs[0]
    transpose_x<<<128, 256, 0, stream>>>(x, xT);

    const int smem_bytes = 32 * 2048 * 2 + 4 * 1152 * 4;  // 149,504 B
    hipFuncSetAttribute((const void*)rnn_arc8, hipFuncAttributeMaxDynamicSharedMemorySize,
                        smem_bytes);
    void* args[] = {(void*)&xT, (void*)&Wx, (void*)&b, (void*)&WhT, (void*)&hs,
                    (void*)&flags};
    hipLaunchCooperativeKernel((const void*)rnn_arc8, dim3(256), dim3(256), args,
                               (unsigned)smem_bytes, stream);

    const unsigned short* hsD = hs + (size_t)B_ * U_;
    decode_gemm2<<<1024, 256, 0, stream>>>(hsD, WdT, bd, out);
}

// Round 14
// 1797.164 us; speedup vs baseline: 1.6748x; 1.0424x over previous
//
#include <hip/hip_runtime.h>
#include <hip/hip_bf16.h>

#define B_ 128
#define T_ 256
#define V_ 256
#define U_ 2048

typedef __bf16 bf16x8 __attribute__((ext_vector_type(8)));
typedef float f32x4 __attribute__((ext_vector_type(4)));
typedef unsigned u32x4 __attribute__((ext_vector_type(4)));

union B8u { uint4 u; bf16x8 v; };

static __device__ inline bf16x8 u2b(uint4 u) { B8u t; t.u = u; return t.v; }
static __device__ inline bf16x8 ldg8(const unsigned short* p) {
    B8u t; t.u = *reinterpret_cast<const uint4*>(p); return t.v;
}
static __device__ inline bf16x8 lds8(const char* smem, unsigned off) {
    B8u t; t.u = *reinterpret_cast<const uint4*>(smem + off); return t.v;
}
static __device__ inline unsigned short f2b(float f) {
    __hip_bfloat16 h = __float2bfloat16(f);
    unsigned short r; __builtin_memcpy(&r, &h, 2); return r;
}
// plain CACHED 16B load as volatile asm: compiler cannot sink it into the
// consumer loop (R3/R4 lesson: sunk loads = serialized latency chain)
static __device__ inline uint4 ldg16_c(const unsigned short* p) {
    uint4 r;
    asm volatile("global_load_dwordx4 %0, %1, off"
                 : "=&v"(r) : "v"(p) : "memory");
    return r;
}
// 16B write-through to L3 coherence point. NOTE: payload must be a NATIVE
// ext_vector (u32x4), not struct uint4 -- clang can't pass a struct as a
// "v" asm input (R13 compile failure).
static __device__ inline void stg16_sc(unsigned short* p, u32x4 v) {
    asm volatile("global_store_dwordx4 %0, %1, off sc0 sc1"
                 :: "v"(p), "v"(v) : "memory");
}
// 4B flag store, write-through (fire-and-forget arrive)
static __device__ inline void stg4_sc_u32(unsigned* p, unsigned v) {
    asm volatile("global_store_dword %0, %1, off sc0 sc1"
                 :: "v"(p), "v"(v) : "memory");
}
// 16B coherent flag load with its own waitcnt (self-contained poll probe)
static __device__ inline uint4 ldg16_sc_wait(const unsigned* p) {
    uint4 r;
    asm volatile("global_load_dwordx4 %0, %1, off sc0 sc1\n\ts_waitcnt vmcnt(0)"
                 : "=&v"(r) : "v"(p) : "memory");
    return r;
}
// tanh via hw exp+rcp (~5 VALU vs ~30 for tanhf); exact at saturation,
// ~2ulp f32 error << bf16 rounding. Validated R11: absmax 0.0098 < 0.0217.
static __device__ inline float tanh_fast(float x) {
    float e = __expf(2.0f * x);
    return 1.0f - 2.0f * __builtin_amdgcn_rcpf(e + 1.0f);
}

// ---------------- prep kernels ----------------

// out[c][r] = bf16(in[r][c]);  in: [R][C] f32, out: [C][R] bf16
__global__ void transpose_bf16(const float* __restrict__ in,
                               unsigned short* __restrict__ outp, int R, int C) {
    __shared__ float tile[32][33];
    int tc = blockIdx.x * 32, tr = blockIdx.y * 32;
    int lx = threadIdx.x & 31, ly = threadIdx.x >> 5;  // 256 thr: ly 0..7
#pragma unroll
    for (int i = 0; i < 32; i += 8)
        tile[ly + i][lx] = in[(size_t)(tr + ly + i) * C + tc + lx];
    __syncthreads();
#pragma unroll
    for (int i = 0; i < 32; i += 8)
        outp[(size_t)(tc + ly + i) * R + tr + lx] = f2b(tile[lx][ly + i]);
}

// fused: h0 -> bf16 hs[0] (all 262144 elems) + x -> xT (first 32768 ids)
__global__ void prep_misc(const float* __restrict__ h0, unsigned short* __restrict__ hb,
                          const int* __restrict__ x, int* __restrict__ xT) {
    int i = blockIdx.x * 256 + threadIdx.x;  // grid: 1024 blocks = B_*U_
    hb[i] = f2b(h0[i]);
    if (i < B_ * T_) {
        int b = i >> 8, t = i & 255;
        xT[t * B_ + b] = x[i];
    }
}

// =====================================================================
// Recurrence kernel -- R12 core + packed 16B h-stores + fast tanh.
// grid: 256 blocks (4 groups x 64), 256 threads (4 waves), 1 block/CU.
// Block (g,p): batches b0=g*32..+32, u-cols c0=p*32..+32.
// Wave w: K-quarter [w*512, +512) -> LDS f32 reduce across waves.
// A loads: plain cached, forced batch-issue via asm, single vmcnt(0).
// h stores: epilogue re-mapped to 128 threads x 8 cols -> ONE dwordx4
// sc0sc1 store per active thread (halves store transactions vs R12).
// arrive: per-wave vmcnt drain + fire-and-forget flag store (R12-proven).
// release: wave 0 polls group's 256 wave-flags (one dwordx4/lane probe)
// with s_sleep backoff, then __syncthreads (also orders red reuse).
// hs archive: fresh address per step -> plain cached reads never stale.
// =====================================================================
__global__ __launch_bounds__(256, 1) void rnn_arc9(
        const int* __restrict__ xT, const float* __restrict__ Wx,
        const float* __restrict__ bias, const unsigned short* __restrict__ WhT,
        unsigned short* __restrict__ hs, unsigned* __restrict__ flags) {
    extern __shared__ char smem[];
    float* red = (float*)(smem + 32 * 2048 * 2);  // [4][32*36] f32

    const int bid = blockIdx.x;
    const int g = bid >> 6, p = bid & 63;
    const int b0 = g * 32, c0 = p * 32;
    const int tid = threadIdx.x;
    const int w = tid >> 6, lane = tid & 63;
    const int lr = lane & 15, lh = lane >> 4;

    // Fill Wh LDS slice: lds[(c*4096 + k8*16) ^ ((c&7)<<4)] = WhT[c0+c][k8*8..+8]
    for (int i = tid; i < 32 * 256; i += 256) {
        int c = i >> 8, k8 = i & 255;
        uint4 v = *reinterpret_cast<const uint4*>(WhT + (size_t)(c0 + c) * U_ + k8 * 8);
        unsigned off = (unsigned)(c * 4096 + k8 * 16) ^ ((unsigned)(c & 7) << 4);
        *reinterpret_cast<uint4*>(smem + off) = v;
    }
    __syncthreads();

    // MFMA-loop constants (wave-local K-quarter)
    const int kbase = w * 512;
    const unsigned lin0 = (unsigned)(lr * 4096) + (unsigned)((kbase + lh * 8) * 2);
    const unsigned lin1 = lin0 + 16 * 4096;
    const unsigned swz = (unsigned)(lr & 7) << 4;

    // epilogue constants: ACTIVE = tid<128; thread -> (row = tid>>2, 8 cols)
    const bool epi = tid < 128;
    const int erow = tid >> 2;              // 0..31 local batch row
    const int ec8 = (tid & 3) * 8;          // 0,8,16,24 local col (x8)
    const int ucol = c0 + ec8;              // global u column of 8-pack
    f32x4 bias4a = {0, 0, 0, 0}, bias4b = {0, 0, 0, 0};
    if (epi) {
        bias4a = *reinterpret_cast<const f32x4*>(bias + ucol);
        bias4b = *reinterpret_cast<const f32x4*>(bias + ucol + 4);
    }

    // sync addresses: flags[g][p][w], poll covers the group's 256 wave-flags
    unsigned* myflag = flags + (unsigned)(g * 256 + p * 4 + w);
    const unsigned* pollp = flags + (unsigned)(g * 256 + lane * 4);

    // x-projection for step 0
    f32x4 xpa = {0, 0, 0, 0}, xpb = {0, 0, 0, 0};
    if (epi) {
        int tok = xT[0 * B_ + b0 + erow];
        const float* wr = Wx + (size_t)tok * U_ + ucol;
        xpa = *reinterpret_cast<const f32x4*>(wr) + bias4a;
        xpb = *reinterpret_cast<const f32x4*>(wr + 4) + bias4b;
    }

    for (int t = 0; t < T_; ++t) {
        const unsigned short* hp = hs + (size_t)t * (B_ * U_);
        unsigned short* hc = hs + (size_t)(t + 1) * (B_ * U_);

        // ---- stage all 32 A-fragments upfront: forced parallel issue ----
        const unsigned short* pa0 = hp + (size_t)(b0 + lr) * U_ + kbase + lh * 8;
        const unsigned short* pa1 = pa0 + 16 * U_;
        uint4 areg0[16], areg1[16];
#pragma unroll
        for (int ks = 0; ks < 16; ++ks) {
            areg0[ks] = ldg16_c(pa0 + ks * 32);
            areg1[ks] = ldg16_c(pa1 + ks * 32);
        }
        asm volatile("s_waitcnt vmcnt(0)" ::: "memory");
        __builtin_amdgcn_sched_barrier(0);

        // ---- load-free MFMA loop over the K-quarter ----
        f32x4 acc00 = {0.f, 0.f, 0.f, 0.f}, acc01 = {0.f, 0.f, 0.f, 0.f};
        f32x4 acc10 = {0.f, 0.f, 0.f, 0.f}, acc11 = {0.f, 0.f, 0.f, 0.f};
#pragma unroll
        for (int ks = 0; ks < 16; ++ks) {
            bf16x8 a0 = u2b(areg0[ks]);
            bf16x8 a1 = u2b(areg1[ks]);
            bf16x8 bb0 = lds8(smem, (lin0 + (unsigned)ks * 64u) ^ swz);
            bf16x8 bb1 = lds8(smem, (lin1 + (unsigned)ks * 64u) ^ swz);
            acc00 = __builtin_amdgcn_mfma_f32_16x16x32_bf16(a0, bb0, acc00, 0, 0, 0);
            acc01 = __builtin_amdgcn_mfma_f32_16x16x32_bf16(a0, bb1, acc01, 0, 0, 0);
            acc10 = __builtin_amdgcn_mfma_f32_16x16x32_bf16(a1, bb0, acc10, 0, 0, 0);
            acc11 = __builtin_amdgcn_mfma_f32_16x16x32_bf16(a1, bb1, acc11, 0, 0, 0);
        }

        // ---- split-K partials -> LDS (C-layout: row=lh*4+r, col=lr) ----
        float* redw = red + w * 1152;
#pragma unroll
        for (int r = 0; r < 4; ++r) {
            redw[(lh * 4 + r) * 36 + lr] = acc00[r];
            redw[(lh * 4 + r) * 36 + 16 + lr] = acc01[r];
            redw[(16 + lh * 4 + r) * 36 + lr] = acc10[r];
            redw[(16 + lh * 4 + r) * 36 + 16 + lr] = acc11[r];
        }
        __syncthreads();  // sync#1: partials visible for the reduce

        // ---- reduce (2x float4) + fast tanh + ONE dwordx4 sc store ----
        if (epi) {
            const int o = erow * 36 + ec8;
            f32x4 za = *reinterpret_cast<f32x4*>(red + 0 * 1152 + o);
            f32x4 zb = *reinterpret_cast<f32x4*>(red + 0 * 1152 + o + 4);
            za += *reinterpret_cast<f32x4*>(red + 1 * 1152 + o);
            zb += *reinterpret_cast<f32x4*>(red + 1 * 1152 + o + 4);
            za += *reinterpret_cast<f32x4*>(red + 2 * 1152 + o);
            zb += *reinterpret_cast<f32x4*>(red + 2 * 1152 + o + 4);
            za += *reinterpret_cast<f32x4*>(red + 3 * 1152 + o);
            zb += *reinterpret_cast<f32x4*>(red + 3 * 1152 + o + 4);
            za += xpa;
            zb += xpb;
            u32x4 pk;
            pk.x = (unsigned)f2b(tanh_fast(za[0])) | ((unsigned)f2b(tanh_fast(za[1])) << 16);
            pk.y = (unsigned)f2b(tanh_fast(za[2])) | ((unsigned)f2b(tanh_fast(za[3])) << 16);
            pk.z = (unsigned)f2b(tanh_fast(zb[0])) | ((unsigned)f2b(tanh_fast(zb[1])) << 16);
            pk.w = (unsigned)f2b(tanh_fast(zb[2])) | ((unsigned)f2b(tanh_fast(zb[3])) << 16);
            stg16_sc(hc + (size_t)(b0 + erow) * U_ + ucol, pk);
        }

        // ---- arrive: per-wave drain of MY h-stores, then one flag store ----
        asm volatile("s_waitcnt vmcnt(0)" ::: "memory");
        if (lane == 0) stg4_sc_u32(myflag, (unsigned)(t + 1));

        // next step's x-projection: issued in the poll window; its latency
        // is covered by next step's vmcnt(0)
        if (epi && t + 1 < T_) {
            int tok = xT[(t + 1) * B_ + b0 + erow];
            const float* wr = Wx + (size_t)tok * U_ + ucol;
            xpa = *reinterpret_cast<const f32x4*>(wr) + bias4a;
            xpb = *reinterpret_cast<const f32x4*>(wr + 4) + bias4b;
        }

        // ---- release: wave 0 polls all 256 group wave-flags (64 lanes x
        //      dwordx4 = one probe) with s_sleep backoff; syncthreads also
        //      orders red reads (this step) vs red writes (next step). ----
        if (t + 1 < T_) {
            if (w == 0) {
                for (;;) {
                    uint4 f = ldg16_sc_wait(pollp);
                    unsigned m01 = f.x < f.y ? f.x : f.y;
                    unsigned m23 = f.z < f.w ? f.z : f.w;
                    unsigned m = m01 < m23 ? m01 : m23;
                    if (__all(m > (unsigned)t)) break;
                    __builtin_amdgcn_s_sleep(1);
                }
            }
            __syncthreads();
        }
    }
}

// =====================================================================
// Decode GEMM v2 (proven in R10): logits[b,t,v] = hs[t+1][b].WdT[v] + bd[v]
// hsD = hs + B*U viewed as [T*B][U]; out row = (b*T + t).
// 1024 blocks x 4 waves; wave = 32 rows x 64 cols; 2 blocks/CU TLP.
// =====================================================================
__global__ __launch_bounds__(256, 2) void decode_gemm2(
        const unsigned short* __restrict__ hsD, const unsigned short* __restrict__ WdT,
        const float* __restrict__ bdv, float* __restrict__ out) {
    const int tid = threadIdx.x;
    const int w = tid >> 6, lane = tid & 63;
    const int lr = lane & 15, lh = lane >> 4;
    const int r0 = blockIdx.x * 32;   // 32 hsD rows per block
    const int v0 = w * 64;            // 64 vocab cols per wave

    const unsigned short* pa0 = hsD + (size_t)(r0 + lr) * U_ + lh * 8;
    const unsigned short* pa1 = pa0 + (size_t)16 * U_;
    const unsigned short* pb0 = WdT + (size_t)(v0 + lr) * U_ + lh * 8;

    f32x4 acc0[4], acc1[4];
#pragma unroll
    for (int n = 0; n < 4; ++n) {
        acc0[n] = (f32x4){0.f, 0.f, 0.f, 0.f};
        acc1[n] = (f32x4){0.f, 0.f, 0.f, 0.f};
    }

#pragma unroll 4
    for (int ks = 0; ks < 64; ++ks) {
        bf16x8 a0 = ldg8(pa0 + ks * 32);
        bf16x8 a1 = ldg8(pa1 + ks * 32);
#pragma unroll
        for (int n = 0; n < 4; ++n) {
            bf16x8 bb = ldg8(pb0 + (size_t)n * 16 * U_ + ks * 32);
            acc0[n] = __builtin_amdgcn_mfma_f32_16x16x32_bf16(a0, bb, acc0[n], 0, 0, 0);
            acc1[n] = __builtin_amdgcn_mfma_f32_16x16x32_bf16(a1, bb, acc1[n], 0, 0, 0);
        }
    }

#pragma unroll
    for (int n = 0; n < 4; ++n) {
        float bd_ = bdv[v0 + n * 16 + lr];
#pragma unroll
        for (int r = 0; r < 4; ++r) {
            int m0 = r0 + lh * 4 + r;        // hsD row = t*B + b
            int m1 = m0 + 16;
            out[((size_t)(m0 & 127) * T_ + (m0 >> 7)) * V_ + v0 + n * 16 + lr] =
                acc0[n][r] + bd_;
            out[((size_t)(m1 & 127) * T_ + (m1 >> 7)) * V_ + v0 + n * 16 + lr] =
                acc1[n][r] + bd_;
        }
    }
}

// ---------------- launch ----------------
extern "C" void kernel_launch(void* const* d_in, const int* in_sizes, int n_in,
                              void* d_out, int out_size, void* d_ws, size_t ws_size,
                              hipStream_t stream) {
    const int* x = (const int*)d_in[0];
    const float* Wx = (const float*)d_in[1];
    const float* Wh = (const float*)d_in[2];
    const float* b = (const float*)d_in[3];
    const float* Wd = (const float*)d_in[4];
    const float* bd = (const float*)d_in[5];
    const float* h0 = (const float*)d_in[6];
    float* out = (float*)d_out;

    char* ws = (char*)d_ws;

    const size_t OFF_WhT = 0;                 // 8,388,608
    const size_t OFF_WdT = 8388608;           // 1,048,576
    const size_t OFF_xT = 9437184;            // 131,072
    const size_t OFF_FLG = 9568256;           // 4,096 (4 grp x 64 blk x 4 wave)
    const size_t OFF_HS = 9572352;            // 257 * 524,288

    unsigned short* WhT = (unsigned short*)(ws + OFF_WhT);
    unsigned short* WdT = (unsigned short*)(ws + OFF_WdT);
    int* xT = (int*)(ws + OFF_xT);
    unsigned* flags = (unsigned*)(ws + OFF_FLG);
    unsigned short* hs = (unsigned short*)(ws + OFF_HS);

    hipMemsetAsync(flags, 0, 4096, stream);
    transpose_bf16<<<dim3(64, 64), 256, 0, stream>>>(Wh, WhT, 2048, 2048);
    transpose_bf16<<<dim3(8, 64), 256, 0, stream>>>(Wd, WdT, 2048, 256);
    prep_misc<<<1024, 256, 0, stream>>>(h0, hs, x, xT);  // h_{-1} -> hs[0] + xT

    const int smem_bytes = 32 * 2048 * 2 + 4 * 1152 * 4;  // 149,504 B
    hipFuncSetAttribute((const void*)rnn_arc9, hipFuncAttributeMaxDynamicSharedMemorySize,
                        smem_bytes);
    void* args[] = {(void*)&xT, (void*)&Wx, (void*)&b, (void*)&WhT, (void*)&hs,
                    (void*)&flags};
    hipLaunchCooperativeKernel((const void*)rnn_arc9, dim3(256), dim3(256), args,
                               (unsigned)smem_bytes, stream);

    const unsigned short* hsD = hs + (size_t)B_ * U_;
    decode_gemm2<<<1024, 256, 0, stream>>>(hsD, WdT, bd, out);
}